// Round 8
// baseline (144.764 us; speedup 1.0000x reference)
//
#include <hip/hip_runtime.h>
#include <hip/hip_bf16.h>

#define NN 8192

using bf16x8 = __attribute__((ext_vector_type(8))) short;
using f32x4  = __attribute__((ext_vector_type(4))) float;

#if __has_builtin(__builtin_amdgcn_exp2f)
#define EXP2(x) __builtin_amdgcn_exp2f(x)
#else
#define EXP2(x) __expf((x) * 0.69314718056f)
#endif

// ---- async global->LDS 16B (wave-uniform base + lane*16 layout) ----
__device__ __forceinline__ void gl_lds16(const void* g, void* l) {
  __builtin_amdgcn_global_load_lds(
      (const __attribute__((address_space(1))) unsigned int*)(unsigned long long)g,
      (__attribute__((address_space(3))) unsigned int*)(unsigned int)(unsigned long long)l,
      16, 0, 0);
}

// ---------------- kernel 1: normalize rows -> bf16, logit_p, zero bandsum+counter ----------------
__global__ __launch_bounds__(256) void k_prep(const float* __restrict__ enc,
                                              const float* __restrict__ dec,
                                              unsigned* __restrict__ Abf,
                                              unsigned* __restrict__ Bbf,
                                              float* __restrict__ logit_p,
                                              float* __restrict__ bandsum,
                                              unsigned* __restrict__ counter) {
  const int t = threadIdx.x;
  const int l16 = t & 15;
  const int row = blockIdx.x * 16 + (t >> 4);
  const int tid = blockIdx.x * 256 + t;
  if (tid < 64 * 256) bandsum[tid] = 0.0f;
  if (tid == 64 * 256) *counter = 0u;

  const float4* e4 = reinterpret_cast<const float4*>(enc) + (size_t)row * 32 + l16 * 2;
  const float4* d4 = reinterpret_cast<const float4*>(dec) + (size_t)row * 32 + l16 * 2;
  float4 e0 = e4[0], e1 = e4[1];
  float4 d0 = d4[0], d1 = d4[1];

  float se = e0.x*e0.x + e0.y*e0.y + e0.z*e0.z + e0.w*e0.w
           + e1.x*e1.x + e1.y*e1.y + e1.z*e1.z + e1.w*e1.w;
  float sd = d0.x*d0.x + d0.y*d0.y + d0.z*d0.z + d0.w*d0.w
           + d1.x*d1.x + d1.y*d1.y + d1.z*d1.z + d1.w*d1.w;
  float sp = e0.x*d0.x + e0.y*d0.y + e0.z*d0.z + e0.w*d0.w
           + e1.x*d1.x + e1.y*d1.y + e1.z*d1.z + e1.w*d1.w;
#pragma unroll
  for (int off = 1; off < 16; off <<= 1) {
    se += __shfl_xor(se, off);
    sd += __shfl_xor(sd, off);
    sp += __shfl_xor(sp, off);
  }
  float ie = rsqrtf(se), id = rsqrtf(sd);

  union { __hip_bfloat162 h; unsigned u; } p;
  uint4 ua, ub;
  p.h = __float22bfloat162_rn(make_float2(e0.x * ie, e0.y * ie)); ua.x = p.u;
  p.h = __float22bfloat162_rn(make_float2(e0.z * ie, e0.w * ie)); ua.y = p.u;
  p.h = __float22bfloat162_rn(make_float2(e1.x * ie, e1.y * ie)); ua.z = p.u;
  p.h = __float22bfloat162_rn(make_float2(e1.z * ie, e1.w * ie)); ua.w = p.u;
  p.h = __float22bfloat162_rn(make_float2(d0.x * id, d0.y * id)); ub.x = p.u;
  p.h = __float22bfloat162_rn(make_float2(d0.z * id, d0.w * id)); ub.y = p.u;
  p.h = __float22bfloat162_rn(make_float2(d1.x * id, d1.y * id)); ub.z = p.u;
  p.h = __float22bfloat162_rn(make_float2(d1.z * id, d1.w * id)); ub.w = p.u;
  reinterpret_cast<uint4*>(Abf)[(size_t)row * 16 + l16] = ua;
  reinterpret_cast<uint4*>(Bbf)[(size_t)row * 16 + l16] = ub;

  if (l16 == 0) {
    float en = se * ie, dn = sd * id;                 // sqrt via x*rsqrt(x)
    float s  = sp / (en * dn + 1e-5f);
    logit_p[row] = -fmaxf(1.25f - s, 0.0f) * (s - 0.75f) * 64.0f;
  }
}

// ---------------- kernel 2: banded bf16 GEMM + register diag sums + last-block tail ----------------
// grid = (64 bands) x (8 splits); each block sweeps 8 tiles. The last block to
// finish its flush runs the scalar lse_p/softplus tail (no dispatch-order assumption).
__global__ __launch_bounds__(256, 2) void k_main(const unsigned short* __restrict__ A,
                                                 const unsigned short* __restrict__ B,
                                                 float* __restrict__ bandsum,
                                                 const float* __restrict__ logit_p,
                                                 unsigned* __restrict__ counter,
                                                 float* __restrict__ out) {
  __shared__ __align__(16) unsigned short As[128 * 128];
  __shared__ __align__(16) unsigned short Bs[128 * 128];
  __shared__ float part[4][256];
  __shared__ unsigned lastFlag;

  const int t  = threadIdx.x;
  const int T  = blockIdx.x;   // band: tiles with (bx-by)&63 == T
  const int sp = blockIdx.y;   // split along the band

#pragma unroll
  for (int q = 0; q < 4; ++q) part[q][t] = 0.0f;

  const int lane = t & 63;
  const int w = t >> 6, wrow = w >> 1, wcol = w & 1;
  const int l15 = lane & 15, quad = lane >> 4;
  const int x7 = l15 & 7;

  const unsigned short* Abase = As + (wrow * 64 + l15) * 128;
  const unsigned short* Bbase = Bs + (wcol * 64 + l15) * 128;
  char* AsB = (char*)As;
  char* BsB = (char*)Bs;

  float dreg[28];
#pragma unroll
  for (int i = 0; i < 28; ++i) dreg[i] = 0.0f;

  // staging: row-within-16 = t>>4, chunk slot = t&15, xor swizzle (j-invariant)
  const int rl_lo = t >> 4;
  const int lgoff = rl_lo * 256 + ((t & 15) ^ (rl_lo & 7)) * 16;  // global byte offset
  const int lloff = t * 16;                                        // LDS byte offset

  // stage tile 0
  {
    const int by = sp * 8;
    const int bx = (by + T) & 63;
    const char* AgT = (const char*)A + (size_t)by * 32768 + lgoff;
    const char* BgT = (const char*)B + (size_t)bx * 32768 + lgoff;
#pragma unroll
    for (int j = 0; j < 8; ++j) {
      gl_lds16(AgT + j * 4096, AsB + lloff + j * 4096);
      gl_lds16(BgT + j * 4096, BsB + lloff + j * 4096);
    }
  }
  __syncthreads();   // drain vmcnt: tile 0 staged

  for (int it = 0; it < 8; ++it) {
    f32x4 acc[4][4];
    const f32x4 zv = {0.f, 0.f, 0.f, 0.f};
#pragma unroll
    for (int r = 0; r < 4; ++r)
#pragma unroll
      for (int c = 0; c < 4; ++c) acc[r][c] = zv;

#pragma unroll
    for (int ks = 0; ks < 4; ++ks) {
      bf16x8 a[4], b[4];
      const int off = ((ks * 4 + quad) ^ x7) * 8;   // swizzled chunk -> element offset
#pragma unroll
      for (int r = 0; r < 4; ++r)
        a[r] = *reinterpret_cast<const bf16x8*>(Abase + r * 16 * 128 + off);
#pragma unroll
      for (int c = 0; c < 4; ++c)
        b[c] = *reinterpret_cast<const bf16x8*>(Bbase + c * 16 * 128 + off);
#pragma unroll
      for (int r = 0; r < 4; ++r)
#pragma unroll
        for (int c = 0; c < 4; ++c)
          acc[r][c] = __builtin_amdgcn_mfma_f32_16x16x32_bf16(a[r], b[c], acc[r][c], 0, 0, 0);
    }

    __syncthreads();   // all ds_reads of this tile done -> LDS reusable

    if (it < 7) {      // issue next tile's async stage; flies under the epilogue
      const int by = sp * 8 + it + 1;
      const int bx = (by + T) & 63;
      const char* AgT = (const char*)A + (size_t)by * 32768 + lgoff;
      const char* BgT = (const char*)B + (size_t)bx * 32768 + lgoff;
#pragma unroll
      for (int j = 0; j < 8; ++j) {
        gl_lds16(AgT + j * 4096, AsB + lloff + j * 4096);
        gl_lds16(BgT + j * 4096, BsB + lloff + j * 4096);
      }
    }

    // ---- epilogue: pure register math, native v_exp ----
    // 64*log2(e) = 92.33248262 ; 0.25*64*log2(e) = 23.08312065
#pragma unroll
    for (int dlt = -3; dlt <= 3; ++dlt) {
#pragma unroll
      for (int g = 0; g < 4; ++g) {
        float s = 0.0f;
#pragma unroll
        for (int r = 0; r < 4; ++r) {
          int c = r + dlt;
          if (c < 0 || c > 3) continue;
          float sn = acc[r][c][g];
          float an = fmaxf(sn + 0.25f, 0.0f);
          float u  = fmaf(sn, 92.332483f, -23.083121f);
          s += EXP2(an * u);
        }
        dreg[(dlt + 3) * 4 + g] += s;
      }
    }

    __syncthreads();   // drain vmcnt: next tile staged
  }

  // ---- single flush: shfl tree over 4-lane collision groups -> LDS -> global ----
  const int  Qoff = (wcol - wrow) * 64 + 127;
  const int  v    = l15 - quad * 4;
  const bool leader = (quad == 0) || (l15 <= 3);
  const bool ok1 = (l15 <= 11) && (quad <= 2);
  const bool ok2 = (l15 <= 7)  && (quad <= 1);

#pragma unroll
  for (int dlt = -3; dlt <= 3; ++dlt) {
#pragma unroll
    for (int g = 0; g < 4; ++g) {
      float s = dreg[(dlt + 3) * 4 + g];
      float t1 = __shfl_down(s, 20); s += ok1 ? t1 : 0.0f;  // partner quad+1
      float t2 = __shfl_down(s, 40); s += ok2 ? t2 : 0.0f;  // partners quad+2, quad+3
      int ld = Qoff + dlt * 16 - g + v;
      if (leader) unsafeAtomicAdd(&part[w][ld], s);         // distinct ld per leader
    }
  }
  __syncthreads();

  // band-0 slot 127 corresponds to d=0 only, which the tail skips
  if (t < 255) {
    float vv = part[0][t] + part[1][t] + part[2][t] + part[3][t];
    unsafeAtomicAdd(&bandsum[T * 256 + t], vv);
  }

  // ---- last-block-done detection ----
  __threadfence();          // make this block's bandsum adds device-visible
  __syncthreads();          // all threads' atomics issued+fenced before the count
  if (t == 0) lastFlag = (atomicAdd(counter, 1u) == 511u) ? 1u : 0u;
  __syncthreads();
  if (!lastFlag) return;

  // ================= scalar tail (one block, 256 threads) =================
  __threadfence();          // acquire: all other blocks' bandsum adds visible
  float* sm = part[0];

  // max of logit_p
  float m = -3.0e38f;
  for (int i = t; i < NN; i += 256) m = fmaxf(m, logit_p[i]);
#pragma unroll
  for (int off = 32; off; off >>= 1) m = fmaxf(m, __shfl_down(m, off));
  if (lane == 0) sm[w] = m;
  __syncthreads();
  m = fmaxf(fmaxf(sm[0], sm[1]), fmaxf(sm[2], sm[3]));
  __syncthreads();

  // sum exp(logit_p - m) -> lse_p
  float s = 0.0f;
  for (int i = t; i < NN; i += 256) s += __expf(logit_p[i] - m);
#pragma unroll
  for (int off = 32; off; off >>= 1) s += __shfl_down(s, off);
  if (lane == 0) sm[w] = s;
  __syncthreads();
  s = sm[0] + sm[1] + sm[2] + sm[3];
  float lse_p = m + __logf(s);
  __syncthreads();

  // per-diagonal band gather + softplus mean over d=1..N-1
  float acc = 0.0f;
  for (int d = t; d < NN; d += 256) {
    if (d == 0) continue;
    int Ta = d >> 7;
    float se = bandsum[Ta * 256 + (d & 127) + 127];
    if (d & 127) {
      int Tb = (Ta + 1) & 63;
      se += bandsum[Tb * 256 + (d & 127) - 1];
    }
    float x = __logf(se) + lse_p;
    acc += fmaxf(x, 0.0f) + __logf(1.0f + __expf(-fabsf(x)));
  }
#pragma unroll
  for (int off = 32; off; off >>= 1) acc += __shfl_down(acc, off);
  if (lane == 0) sm[w] = acc;
  __syncthreads();
  if (t == 0) out[0] = (sm[0] + sm[1] + sm[2] + sm[3]) * (1.0f / 8191.0f);
}

// ---------------- launcher ----------------
extern "C" void kernel_launch(void* const* d_in, const int* in_sizes, int n_in,
                              void* d_out, int out_size, void* d_ws, size_t ws_size,
                              hipStream_t stream) {
  const float* enc = (const float*)d_in[0];
  const float* dec = (const float*)d_in[1];
  float* ws = (float*)d_ws;

  float*    logit_p = ws;                               // 8192
  float*    bandsum = ws + 8192;                        // 64*256 = 16384
  unsigned* counter = (unsigned*)(ws + 8192 + 16384);   // 1
  unsigned* Abf     = (unsigned*)(ws + 8192 + 16384 + 256);  // 8192x128 bf16 = 2 MB
  unsigned* Bbf     = Abf + 524288;
  float*    out     = (float*)d_out;

  k_prep<<<NN / 16, 256, 0, stream>>>(enc, dec, Abf, Bbf, logit_p, bandsum, counter);
  dim3 grid(64, 8);
  k_main<<<grid, 256, 0, stream>>>((const unsigned short*)Abf, (const unsigned short*)Bbf,
                                   bandsum, logit_p, counter, out);
}

// Round 9
// 118.837 us; speedup vs baseline: 1.2182x; 1.2182x over previous
//
#include <hip/hip_runtime.h>
#include <hip/hip_bf16.h>

#define NN 8192

using bf16x8 = __attribute__((ext_vector_type(8))) short;
using f32x4  = __attribute__((ext_vector_type(4))) float;

#if __has_builtin(__builtin_amdgcn_exp2f)
#define EXP2(x) __builtin_amdgcn_exp2f(x)
#else
#define EXP2(x) __expf((x) * 0.69314718056f)
#endif

// ---- async global->LDS 16B (wave-uniform base + lane*16 layout) ----
__device__ __forceinline__ void gl_lds16(const void* g, void* l) {
  __builtin_amdgcn_global_load_lds(
      (const __attribute__((address_space(1))) unsigned int*)(unsigned long long)g,
      (__attribute__((address_space(3))) unsigned int*)(unsigned int)(unsigned long long)l,
      16, 0, 0);
}

// ---------------- kernel 1: normalize rows -> bf16, logit_p, zero bandsum+counter ----------------
__global__ __launch_bounds__(256) void k_prep(const float* __restrict__ enc,
                                              const float* __restrict__ dec,
                                              unsigned* __restrict__ Abf,
                                              unsigned* __restrict__ Bbf,
                                              float* __restrict__ logit_p,
                                              float* __restrict__ bandsum,
                                              unsigned* __restrict__ counter) {
  const int t = threadIdx.x;
  const int l16 = t & 15;
  const int row = blockIdx.x * 16 + (t >> 4);
  const int tid = blockIdx.x * 256 + t;
  if (tid < 64 * 256) bandsum[tid] = 0.0f;
  if (tid == 64 * 256) *counter = 0u;

  const float4* e4 = reinterpret_cast<const float4*>(enc) + (size_t)row * 32 + l16 * 2;
  const float4* d4 = reinterpret_cast<const float4*>(dec) + (size_t)row * 32 + l16 * 2;
  float4 e0 = e4[0], e1 = e4[1];
  float4 d0 = d4[0], d1 = d4[1];

  float se = e0.x*e0.x + e0.y*e0.y + e0.z*e0.z + e0.w*e0.w
           + e1.x*e1.x + e1.y*e1.y + e1.z*e1.z + e1.w*e1.w;
  float sd = d0.x*d0.x + d0.y*d0.y + d0.z*d0.z + d0.w*d0.w
           + d1.x*d1.x + d1.y*d1.y + d1.z*d1.z + d1.w*d1.w;
  float sp = e0.x*d0.x + e0.y*d0.y + e0.z*d0.z + e0.w*d0.w
           + e1.x*d1.x + e1.y*d1.y + e1.z*d1.z + e1.w*d1.w;
#pragma unroll
  for (int off = 1; off < 16; off <<= 1) {
    se += __shfl_xor(se, off);
    sd += __shfl_xor(sd, off);
    sp += __shfl_xor(sp, off);
  }
  float ie = rsqrtf(se), id = rsqrtf(sd);

  union { __hip_bfloat162 h; unsigned u; } p;
  uint4 ua, ub;
  p.h = __float22bfloat162_rn(make_float2(e0.x * ie, e0.y * ie)); ua.x = p.u;
  p.h = __float22bfloat162_rn(make_float2(e0.z * ie, e0.w * ie)); ua.y = p.u;
  p.h = __float22bfloat162_rn(make_float2(e1.x * ie, e1.y * ie)); ua.z = p.u;
  p.h = __float22bfloat162_rn(make_float2(e1.z * ie, e1.w * ie)); ua.w = p.u;
  p.h = __float22bfloat162_rn(make_float2(d0.x * id, d0.y * id)); ub.x = p.u;
  p.h = __float22bfloat162_rn(make_float2(d0.z * id, d0.w * id)); ub.y = p.u;
  p.h = __float22bfloat162_rn(make_float2(d1.x * id, d1.y * id)); ub.z = p.u;
  p.h = __float22bfloat162_rn(make_float2(d1.z * id, d1.w * id)); ub.w = p.u;
  reinterpret_cast<uint4*>(Abf)[(size_t)row * 16 + l16] = ua;
  reinterpret_cast<uint4*>(Bbf)[(size_t)row * 16 + l16] = ub;

  if (l16 == 0) {
    float en = se * ie, dn = sd * id;                 // sqrt via x*rsqrt(x)
    float s  = sp / (en * dn + 1e-5f);
    logit_p[row] = -fmaxf(1.25f - s, 0.0f) * (s - 0.75f) * 64.0f;
  }
}

// ---------------- kernel 2: banded bf16 GEMM + register diag sums + last-block tail ----------------
// grid = (64 bands) x (8 splits); each block sweeps 8 tiles. The last block to
// finish its flush runs the scalar lse_p/softplus tail.
// NOTE: no release __threadfence() per block — bandsum flush uses device-scope
// atomics (performed at the device coherence point) and __syncthreads() emits
// s_waitcnt vmcnt(0), so the counter atomicAdd is ordered after them. The 512x
// agent-fence (buffer_wbl2 L2-writeback) was the R8 regression (+45 us stall).
__global__ __launch_bounds__(256, 2) void k_main(const unsigned short* __restrict__ A,
                                                 const unsigned short* __restrict__ B,
                                                 float* __restrict__ bandsum,
                                                 const float* __restrict__ logit_p,
                                                 unsigned* __restrict__ counter,
                                                 float* __restrict__ out) {
  __shared__ __align__(16) unsigned short As[128 * 128];
  __shared__ __align__(16) unsigned short Bs[128 * 128];
  __shared__ float part[4][256];
  __shared__ unsigned lastFlag;

  const int t  = threadIdx.x;
  const int T  = blockIdx.x;   // band: tiles with (bx-by)&63 == T
  const int sp = blockIdx.y;   // split along the band

#pragma unroll
  for (int q = 0; q < 4; ++q) part[q][t] = 0.0f;

  const int lane = t & 63;
  const int w = t >> 6, wrow = w >> 1, wcol = w & 1;
  const int l15 = lane & 15, quad = lane >> 4;
  const int x7 = l15 & 7;

  const unsigned short* Abase = As + (wrow * 64 + l15) * 128;
  const unsigned short* Bbase = Bs + (wcol * 64 + l15) * 128;
  char* AsB = (char*)As;
  char* BsB = (char*)Bs;

  float dreg[28];
#pragma unroll
  for (int i = 0; i < 28; ++i) dreg[i] = 0.0f;

  // staging: row-within-16 = t>>4, chunk slot = t&15, xor swizzle (j-invariant)
  const int rl_lo = t >> 4;
  const int lgoff = rl_lo * 256 + ((t & 15) ^ (rl_lo & 7)) * 16;  // global byte offset
  const int lloff = t * 16;                                        // LDS byte offset

  // stage tile 0
  {
    const int by = sp * 8;
    const int bx = (by + T) & 63;
    const char* AgT = (const char*)A + (size_t)by * 32768 + lgoff;
    const char* BgT = (const char*)B + (size_t)bx * 32768 + lgoff;
#pragma unroll
    for (int j = 0; j < 8; ++j) {
      gl_lds16(AgT + j * 4096, AsB + lloff + j * 4096);
      gl_lds16(BgT + j * 4096, BsB + lloff + j * 4096);
    }
  }
  __syncthreads();   // drain vmcnt: tile 0 staged

  for (int it = 0; it < 8; ++it) {
    f32x4 acc[4][4];
    const f32x4 zv = {0.f, 0.f, 0.f, 0.f};
#pragma unroll
    for (int r = 0; r < 4; ++r)
#pragma unroll
      for (int c = 0; c < 4; ++c) acc[r][c] = zv;

#pragma unroll
    for (int ks = 0; ks < 4; ++ks) {
      bf16x8 a[4], b[4];
      const int off = ((ks * 4 + quad) ^ x7) * 8;   // swizzled chunk -> element offset
#pragma unroll
      for (int r = 0; r < 4; ++r)
        a[r] = *reinterpret_cast<const bf16x8*>(Abase + r * 16 * 128 + off);
#pragma unroll
      for (int c = 0; c < 4; ++c)
        b[c] = *reinterpret_cast<const bf16x8*>(Bbase + c * 16 * 128 + off);
#pragma unroll
      for (int r = 0; r < 4; ++r)
#pragma unroll
        for (int c = 0; c < 4; ++c)
          acc[r][c] = __builtin_amdgcn_mfma_f32_16x16x32_bf16(a[r], b[c], acc[r][c], 0, 0, 0);
    }

    __syncthreads();   // all ds_reads of this tile done -> LDS reusable

    if (it < 7) {      // issue next tile's async stage; flies under the epilogue
      const int by = sp * 8 + it + 1;
      const int bx = (by + T) & 63;
      const char* AgT = (const char*)A + (size_t)by * 32768 + lgoff;
      const char* BgT = (const char*)B + (size_t)bx * 32768 + lgoff;
#pragma unroll
      for (int j = 0; j < 8; ++j) {
        gl_lds16(AgT + j * 4096, AsB + lloff + j * 4096);
        gl_lds16(BgT + j * 4096, BsB + lloff + j * 4096);
      }
    }

    // ---- epilogue: pure register math, native v_exp ----
    // 64*log2(e) = 92.33248262 ; 0.25*64*log2(e) = 23.08312065
#pragma unroll
    for (int dlt = -3; dlt <= 3; ++dlt) {
#pragma unroll
      for (int g = 0; g < 4; ++g) {
        float s = 0.0f;
#pragma unroll
        for (int r = 0; r < 4; ++r) {
          int c = r + dlt;
          if (c < 0 || c > 3) continue;
          float sn = acc[r][c][g];
          float an = fmaxf(sn + 0.25f, 0.0f);
          float u  = fmaf(sn, 92.332483f, -23.083121f);
          s += EXP2(an * u);
        }
        dreg[(dlt + 3) * 4 + g] += s;
      }
    }

    __syncthreads();   // drain vmcnt: next tile staged
  }

  // ---- single flush: shfl tree over 4-lane collision groups -> LDS -> global ----
  const int  Qoff = (wcol - wrow) * 64 + 127;
  const int  v    = l15 - quad * 4;
  const bool leader = (quad == 0) || (l15 <= 3);
  const bool ok1 = (l15 <= 11) && (quad <= 2);
  const bool ok2 = (l15 <= 7)  && (quad <= 1);

#pragma unroll
  for (int dlt = -3; dlt <= 3; ++dlt) {
#pragma unroll
    for (int g = 0; g < 4; ++g) {
      float s = dreg[(dlt + 3) * 4 + g];
      float t1 = __shfl_down(s, 20); s += ok1 ? t1 : 0.0f;  // partner quad+1
      float t2 = __shfl_down(s, 40); s += ok2 ? t2 : 0.0f;  // partners quad+2, quad+3
      int ld = Qoff + dlt * 16 - g + v;
      if (leader) unsafeAtomicAdd(&part[w][ld], s);         // distinct ld per leader
    }
  }
  __syncthreads();

  // band-0 slot 127 corresponds to d=0 only, which the tail skips
  if (t < 255) {
    float vv = part[0][t] + part[1][t] + part[2][t] + part[3][t];
    unsafeAtomicAdd(&bandsum[T * 256 + t], vv);
  }

  // ---- last-block-done detection (no release fence: see kernel comment) ----
  __syncthreads();          // s_waitcnt vmcnt(0): bandsum atomics performed
  if (t == 0) lastFlag = (atomicAdd(counter, 1u) == 511u) ? 1u : 0u;
  __syncthreads();
  if (!lastFlag) return;

  // ================= scalar tail (one block, 256 threads) =================
  __threadfence();          // acquire: invalidate L1/L2 so bandsum loads are fresh
  float* sm = part[0];

  // max of logit_p
  float m = -3.0e38f;
  for (int i = t; i < NN; i += 256) m = fmaxf(m, logit_p[i]);
#pragma unroll
  for (int off = 32; off; off >>= 1) m = fmaxf(m, __shfl_down(m, off));
  if (lane == 0) sm[w] = m;
  __syncthreads();
  m = fmaxf(fmaxf(sm[0], sm[1]), fmaxf(sm[2], sm[3]));
  __syncthreads();

  // sum exp(logit_p - m) -> lse_p
  float s = 0.0f;
  for (int i = t; i < NN; i += 256) s += __expf(logit_p[i] - m);
#pragma unroll
  for (int off = 32; off; off >>= 1) s += __shfl_down(s, off);
  if (lane == 0) sm[w] = s;
  __syncthreads();
  s = sm[0] + sm[1] + sm[2] + sm[3];
  float lse_p = m + __logf(s);
  __syncthreads();

  // per-diagonal band gather + softplus mean over d=1..N-1
  float acc = 0.0f;
  for (int d = t; d < NN; d += 256) {
    if (d == 0) continue;
    int Ta = d >> 7;
    float se = bandsum[Ta * 256 + (d & 127) + 127];
    if (d & 127) {
      int Tb = (Ta + 1) & 63;
      se += bandsum[Tb * 256 + (d & 127) - 1];
    }
    float x = __logf(se) + lse_p;
    acc += fmaxf(x, 0.0f) + __logf(1.0f + __expf(-fabsf(x)));
  }
#pragma unroll
  for (int off = 32; off; off >>= 1) acc += __shfl_down(acc, off);
  if (lane == 0) sm[w] = acc;
  __syncthreads();
  if (t == 0) out[0] = (sm[0] + sm[1] + sm[2] + sm[3]) * (1.0f / 8191.0f);
}

// ---------------- launcher ----------------
extern "C" void kernel_launch(void* const* d_in, const int* in_sizes, int n_in,
                              void* d_out, int out_size, void* d_ws, size_t ws_size,
                              hipStream_t stream) {
  const float* enc = (const float*)d_in[0];
  const float* dec = (const float*)d_in[1];
  float* ws = (float*)d_ws;

  float*    logit_p = ws;                               // 8192
  float*    bandsum = ws + 8192;                        // 64*256 = 16384
  unsigned* counter = (unsigned*)(ws + 8192 + 16384);   // 1
  unsigned* Abf     = (unsigned*)(ws + 8192 + 16384 + 256);  // 8192x128 bf16 = 2 MB
  unsigned* Bbf     = Abf + 524288;
  float*    out     = (float*)d_out;

  k_prep<<<NN / 16, 256, 0, stream>>>(enc, dec, Abf, Bbf, logit_p, bandsum, counter);
  dim3 grid(64, 8);
  k_main<<<grid, 256, 0, stream>>>((const unsigned short*)Abf, (const unsigned short*)Bbf,
                                   bandsum, logit_p, counter, out);
}

// Round 10
// 102.679 us; speedup vs baseline: 1.4099x; 1.1574x over previous
//
#include <hip/hip_runtime.h>
#include <hip/hip_bf16.h>

#define NN 8192

using bf16x8 = __attribute__((ext_vector_type(8))) short;
using f32x4  = __attribute__((ext_vector_type(4))) float;

#if __has_builtin(__builtin_amdgcn_exp2f)
#define EXP2(x) __builtin_amdgcn_exp2f(x)
#else
#define EXP2(x) __expf((x) * 0.69314718056f)
#endif

// ---- async global->LDS 16B (wave-uniform base + lane*16 layout) ----
__device__ __forceinline__ void gl_lds16(const void* g, void* l) {
  __builtin_amdgcn_global_load_lds(
      (const __attribute__((address_space(1))) unsigned int*)(unsigned long long)g,
      (__attribute__((address_space(3))) unsigned int*)(unsigned int)(unsigned long long)l,
      16, 0, 0);
}

// ---------------- kernel 1: normalize rows -> bf16, logit_p, zero bandsum+counter ----------------
__global__ __launch_bounds__(256) void k_prep(const float* __restrict__ enc,
                                              const float* __restrict__ dec,
                                              unsigned* __restrict__ Abf,
                                              unsigned* __restrict__ Bbf,
                                              float* __restrict__ logit_p,
                                              float* __restrict__ bandsum,
                                              unsigned* __restrict__ counter) {
  const int t = threadIdx.x;
  const int l16 = t & 15;
  const int row = blockIdx.x * 16 + (t >> 4);
  const int tid = blockIdx.x * 256 + t;
  if (tid < 64 * 256) bandsum[tid] = 0.0f;
  if (tid == 64 * 256) *counter = 0u;

  const float4* e4 = reinterpret_cast<const float4*>(enc) + (size_t)row * 32 + l16 * 2;
  const float4* d4 = reinterpret_cast<const float4*>(dec) + (size_t)row * 32 + l16 * 2;
  float4 e0 = e4[0], e1 = e4[1];
  float4 d0 = d4[0], d1 = d4[1];

  float se = e0.x*e0.x + e0.y*e0.y + e0.z*e0.z + e0.w*e0.w
           + e1.x*e1.x + e1.y*e1.y + e1.z*e1.z + e1.w*e1.w;
  float sd = d0.x*d0.x + d0.y*d0.y + d0.z*d0.z + d0.w*d0.w
           + d1.x*d1.x + d1.y*d1.y + d1.z*d1.z + d1.w*d1.w;
  float sp = e0.x*d0.x + e0.y*d0.y + e0.z*d0.z + e0.w*d0.w
           + e1.x*d1.x + e1.y*d1.y + e1.z*d1.z + e1.w*d1.w;
#pragma unroll
  for (int off = 1; off < 16; off <<= 1) {
    se += __shfl_xor(se, off);
    sd += __shfl_xor(sd, off);
    sp += __shfl_xor(sp, off);
  }
  float ie = rsqrtf(se), id = rsqrtf(sd);

  union { __hip_bfloat162 h; unsigned u; } p;
  uint4 ua, ub;
  p.h = __float22bfloat162_rn(make_float2(e0.x * ie, e0.y * ie)); ua.x = p.u;
  p.h = __float22bfloat162_rn(make_float2(e0.z * ie, e0.w * ie)); ua.y = p.u;
  p.h = __float22bfloat162_rn(make_float2(e1.x * ie, e1.y * ie)); ua.z = p.u;
  p.h = __float22bfloat162_rn(make_float2(e1.z * ie, e1.w * ie)); ua.w = p.u;
  p.h = __float22bfloat162_rn(make_float2(d0.x * id, d0.y * id)); ub.x = p.u;
  p.h = __float22bfloat162_rn(make_float2(d0.z * id, d0.w * id)); ub.y = p.u;
  p.h = __float22bfloat162_rn(make_float2(d1.x * id, d1.y * id)); ub.z = p.u;
  p.h = __float22bfloat162_rn(make_float2(d1.z * id, d1.w * id)); ub.w = p.u;
  reinterpret_cast<uint4*>(Abf)[(size_t)row * 16 + l16] = ua;
  reinterpret_cast<uint4*>(Bbf)[(size_t)row * 16 + l16] = ub;

  if (l16 == 0) {
    float en = se * ie, dn = sd * id;                 // sqrt via x*rsqrt(x)
    float s  = sp / (en * dn + 1e-5f);
    logit_p[row] = -fmaxf(1.25f - s, 0.0f) * (s - 0.75f) * 64.0f;
  }
}

// ---------------- kernel 2: banded bf16 GEMM + register diag sums + last-block tail ----------------
// grid = (64 bands) x (8 splits); each block sweeps 8 tiles. The last block to
// finish its flush runs the scalar lse_p/softplus tail with BATCHED loads
// (all 32 loads per pass in flight at once: post-fence loads are HBM misses,
// ~900 cyc each — serial issue was the R9 ~20 us single-block tail window).
__global__ __launch_bounds__(256, 2) void k_main(const unsigned short* __restrict__ A,
                                                 const unsigned short* __restrict__ B,
                                                 float* __restrict__ bandsum,
                                                 const float* __restrict__ logit_p,
                                                 unsigned* __restrict__ counter,
                                                 float* __restrict__ out) {
  __shared__ __align__(16) unsigned short As[128 * 128];
  __shared__ __align__(16) unsigned short Bs[128 * 128];
  __shared__ float part[4][256];
  __shared__ unsigned lastFlag;

  const int t  = threadIdx.x;
  const int T  = blockIdx.x;   // band: tiles with (bx-by)&63 == T
  const int sp = blockIdx.y;   // split along the band

#pragma unroll
  for (int q = 0; q < 4; ++q) part[q][t] = 0.0f;

  const int lane = t & 63;
  const int w = t >> 6, wrow = w >> 1, wcol = w & 1;
  const int l15 = lane & 15, quad = lane >> 4;
  const int x7 = l15 & 7;

  const unsigned short* Abase = As + (wrow * 64 + l15) * 128;
  const unsigned short* Bbase = Bs + (wcol * 64 + l15) * 128;
  char* AsB = (char*)As;
  char* BsB = (char*)Bs;

  float dreg[28];
#pragma unroll
  for (int i = 0; i < 28; ++i) dreg[i] = 0.0f;

  // staging: row-within-16 = t>>4, chunk slot = t&15, xor swizzle (j-invariant)
  const int rl_lo = t >> 4;
  const int lgoff = rl_lo * 256 + ((t & 15) ^ (rl_lo & 7)) * 16;  // global byte offset
  const int lloff = t * 16;                                        // LDS byte offset

  // stage tile 0
  {
    const int by = sp * 8;
    const int bx = (by + T) & 63;
    const char* AgT = (const char*)A + (size_t)by * 32768 + lgoff;
    const char* BgT = (const char*)B + (size_t)bx * 32768 + lgoff;
#pragma unroll
    for (int j = 0; j < 8; ++j) {
      gl_lds16(AgT + j * 4096, AsB + lloff + j * 4096);
      gl_lds16(BgT + j * 4096, BsB + lloff + j * 4096);
    }
  }
  __syncthreads();   // drain vmcnt: tile 0 staged

  for (int it = 0; it < 8; ++it) {
    f32x4 acc[4][4];
    const f32x4 zv = {0.f, 0.f, 0.f, 0.f};
#pragma unroll
    for (int r = 0; r < 4; ++r)
#pragma unroll
      for (int c = 0; c < 4; ++c) acc[r][c] = zv;

#pragma unroll
    for (int ks = 0; ks < 4; ++ks) {
      bf16x8 a[4], b[4];
      const int off = ((ks * 4 + quad) ^ x7) * 8;   // swizzled chunk -> element offset
#pragma unroll
      for (int r = 0; r < 4; ++r)
        a[r] = *reinterpret_cast<const bf16x8*>(Abase + r * 16 * 128 + off);
#pragma unroll
      for (int c = 0; c < 4; ++c)
        b[c] = *reinterpret_cast<const bf16x8*>(Bbase + c * 16 * 128 + off);
#pragma unroll
      for (int r = 0; r < 4; ++r)
#pragma unroll
        for (int c = 0; c < 4; ++c)
          acc[r][c] = __builtin_amdgcn_mfma_f32_16x16x32_bf16(a[r], b[c], acc[r][c], 0, 0, 0);
    }

    __syncthreads();   // all ds_reads of this tile done -> LDS reusable

    if (it < 7) {      // issue next tile's async stage; flies under the epilogue
      const int by = sp * 8 + it + 1;
      const int bx = (by + T) & 63;
      const char* AgT = (const char*)A + (size_t)by * 32768 + lgoff;
      const char* BgT = (const char*)B + (size_t)bx * 32768 + lgoff;
#pragma unroll
      for (int j = 0; j < 8; ++j) {
        gl_lds16(AgT + j * 4096, AsB + lloff + j * 4096);
        gl_lds16(BgT + j * 4096, BsB + lloff + j * 4096);
      }
    }

    // ---- epilogue: pure register math, native v_exp ----
    // 64*log2(e) = 92.33248262 ; 0.25*64*log2(e) = 23.08312065
#pragma unroll
    for (int dlt = -3; dlt <= 3; ++dlt) {
#pragma unroll
      for (int g = 0; g < 4; ++g) {
        float s = 0.0f;
#pragma unroll
        for (int r = 0; r < 4; ++r) {
          int c = r + dlt;
          if (c < 0 || c > 3) continue;
          float sn = acc[r][c][g];
          float an = fmaxf(sn + 0.25f, 0.0f);
          float u  = fmaf(sn, 92.332483f, -23.083121f);
          s += EXP2(an * u);
        }
        dreg[(dlt + 3) * 4 + g] += s;
      }
    }

    __syncthreads();   // drain vmcnt: next tile staged
  }

  // ---- single flush: shfl tree over 4-lane collision groups -> LDS -> global ----
  const int  Qoff = (wcol - wrow) * 64 + 127;
  const int  v    = l15 - quad * 4;
  const bool leader = (quad == 0) || (l15 <= 3);
  const bool ok1 = (l15 <= 11) && (quad <= 2);
  const bool ok2 = (l15 <= 7)  && (quad <= 1);

#pragma unroll
  for (int dlt = -3; dlt <= 3; ++dlt) {
#pragma unroll
    for (int g = 0; g < 4; ++g) {
      float s = dreg[(dlt + 3) * 4 + g];
      float t1 = __shfl_down(s, 20); s += ok1 ? t1 : 0.0f;  // partner quad+1
      float t2 = __shfl_down(s, 40); s += ok2 ? t2 : 0.0f;  // partners quad+2, quad+3
      int ld = Qoff + dlt * 16 - g + v;
      if (leader) unsafeAtomicAdd(&part[w][ld], s);         // distinct ld per leader
    }
  }
  __syncthreads();

  // band-0 slot 127 corresponds to d=0 only, which the tail skips
  if (t < 255) {
    float vv = part[0][t] + part[1][t] + part[2][t] + part[3][t];
    unsafeAtomicAdd(&bandsum[T * 256 + t], vv);
  }

  // ---- last-block-done detection (no release fence: device-scope atomics +
  //      the vmcnt(0) in __syncthreads order them before the counter bump) ----
  __syncthreads();
  if (t == 0) lastFlag = (atomicAdd(counter, 1u) == 511u) ? 1u : 0u;
  __syncthreads();
  if (!lastFlag) return;

  // ================= scalar tail (one block, 256 threads, batched loads) =================
  __threadfence();          // acquire: invalidate stale lines so bandsum loads are fresh
  float* sm = part[0];

  // ---- batched load of this thread's 32 logit_p values (one latency payment) ----
  float lp[32];
#pragma unroll
  for (int k = 0; k < 32; ++k) lp[k] = logit_p[t + 256 * k];

  float m = lp[0];
#pragma unroll
  for (int k = 1; k < 32; ++k) m = fmaxf(m, lp[k]);
#pragma unroll
  for (int off = 32; off; off >>= 1) m = fmaxf(m, __shfl_down(m, off));
  if (lane == 0) sm[w] = m;
  __syncthreads();
  m = fmaxf(fmaxf(sm[0], sm[1]), fmaxf(sm[2], sm[3]));
  __syncthreads();

  float s = 0.0f;
#pragma unroll
  for (int k = 0; k < 32; ++k) s += __expf(lp[k] - m);
#pragma unroll
  for (int off = 32; off; off >>= 1) s += __shfl_down(s, off);
  if (lane == 0) sm[w] = s;
  __syncthreads();
  s = sm[0] + sm[1] + sm[2] + sm[3];
  float lse_p = m + __logf(s);
  __syncthreads();

  // ---- batched gather of bandsum operands, then softplus mean over d=1..N-1 ----
  // thread t handles d = t + 256k: d>>7 = (t>>7) + 2k, d&127 = t&127
  const int o  = t & 127;
  const int hi = t >> 7;
  float bs1[32], bs2[32];
#pragma unroll
  for (int k = 0; k < 32; ++k) {
    int Ta = hi + 2 * k;
    bs1[k] = bandsum[Ta * 256 + o + 127];
    bs2[k] = o ? bandsum[((Ta + 1) & 63) * 256 + o - 1] : 0.0f;
  }
  float acc = 0.0f;
#pragma unroll
  for (int k = 0; k < 32; ++k) {
    if (t == 0 && k == 0) continue;   // d=0 excluded
    float se = bs1[k] + bs2[k];
    float x = __logf(se) + lse_p;
    acc += fmaxf(x, 0.0f) + __logf(1.0f + __expf(-fabsf(x)));
  }
#pragma unroll
  for (int off = 32; off; off >>= 1) acc += __shfl_down(acc, off);
  if (lane == 0) sm[w] = acc;
  __syncthreads();
  if (t == 0) out[0] = (sm[0] + sm[1] + sm[2] + sm[3]) * (1.0f / 8191.0f);
}

// ---------------- launcher ----------------
extern "C" void kernel_launch(void* const* d_in, const int* in_sizes, int n_in,
                              void* d_out, int out_size, void* d_ws, size_t ws_size,
                              hipStream_t stream) {
  const float* enc = (const float*)d_in[0];
  const float* dec = (const float*)d_in[1];
  float* ws = (float*)d_ws;

  float*    logit_p = ws;                               // 8192
  float*    bandsum = ws + 8192;                        // 64*256 = 16384
  unsigned* counter = (unsigned*)(ws + 8192 + 16384);   // 1
  unsigned* Abf     = (unsigned*)(ws + 8192 + 16384 + 256);  // 8192x128 bf16 = 2 MB
  unsigned* Bbf     = Abf + 524288;
  float*    out     = (float*)d_out;

  k_prep<<<NN / 16, 256, 0, stream>>>(enc, dec, Abf, Bbf, logit_p, bandsum, counter);
  dim3 grid(64, 8);
  k_main<<<grid, 256, 0, stream>>>((const unsigned short*)Abf, (const unsigned short*)Bbf,
                                   bandsum, logit_p, counter, out);
}

// Round 11
// 96.375 us; speedup vs baseline: 1.5021x; 1.0654x over previous
//
#include <hip/hip_runtime.h>
#include <hip/hip_bf16.h>

#define NN 8192

using f32x4 = __attribute__((ext_vector_type(4))) float;

#if __has_builtin(__builtin_amdgcn_exp2f)
#define EXP2(x) __builtin_amdgcn_exp2f(x)
#else
#define EXP2(x) __expf((x) * 0.69314718056f)
#endif

// ---- async global->LDS 16B (wave-uniform base + lane*16 layout) ----
__device__ __forceinline__ void gl_lds16(const void* g, void* l) {
  __builtin_amdgcn_global_load_lds(
      (const __attribute__((address_space(1))) unsigned int*)(unsigned long long)g,
      (__attribute__((address_space(3))) unsigned int*)(unsigned int)(unsigned long long)l,
      16, 0, 0);
}

// ---- fp8 e4m3 (OCP) pack: 4 floats -> 4 bytes ----
#if __has_builtin(__builtin_amdgcn_cvt_pk_fp8_f32)
__device__ __forceinline__ unsigned pk4_fp8(float x0, float x1, float x2, float x3) {
  unsigned w = (unsigned)__builtin_amdgcn_cvt_pk_fp8_f32(x0, x1, 0, false);
  w = (unsigned)__builtin_amdgcn_cvt_pk_fp8_f32(x2, x3, (int)w, true);
  return w;
}
#else
__device__ __forceinline__ unsigned f8_1(float f) {   // scalar e4m3fn RNE fallback
  unsigned u = __float_as_uint(f);
  unsigned s = (u >> 24) & 0x80u;
  float a = fabsf(f);
  if (a < 0.015625f) {                                 // subnormal: step 2^-9
    unsigned m = (unsigned)rintf(a * 512.0f);
    return s | (m > 7u ? 8u : m);                      // carries into exp 1 naturally
  }
  if (a > 448.0f) return s | 0x7Eu;
  unsigned au = u & 0x7FFFFFFFu;
  unsigned e = (au >> 23) - 127u + 7u;                 // e4m3 biased exponent
  unsigned m23 = au & 0x7FFFFFu;
  unsigned m = m23 >> 20;
  unsigned rem = m23 & 0xFFFFFu;
  if (rem > 0x80000u || (rem == 0x80000u && (m & 1u))) {
    if (++m == 8u) { m = 0u; ++e; }
  }
  return s | (e << 3) | m;
}
__device__ __forceinline__ unsigned pk4_fp8(float x0, float x1, float x2, float x3) {
  return f8_1(x0) | (f8_1(x1) << 8) | (f8_1(x2) << 16) | (f8_1(x3) << 24);
}
#endif

// ---------------- kernel 1: normalize rows -> fp8, logit_p, zero bandsum+counter ----------------
__global__ __launch_bounds__(256) void k_prep(const float* __restrict__ enc,
                                              const float* __restrict__ dec,
                                              uint2* __restrict__ A8,
                                              uint2* __restrict__ B8,
                                              float* __restrict__ logit_p,
                                              float* __restrict__ bandsum,
                                              unsigned* __restrict__ counter) {
  const int t = threadIdx.x;
  const int l16 = t & 15;
  const int row = blockIdx.x * 16 + (t >> 4);
  const int tid = blockIdx.x * 256 + t;
  if (tid < 64 * 256) bandsum[tid] = 0.0f;
  if (tid == 64 * 256) *counter = 0u;

  const float4* e4 = reinterpret_cast<const float4*>(enc) + (size_t)row * 32 + l16 * 2;
  const float4* d4 = reinterpret_cast<const float4*>(dec) + (size_t)row * 32 + l16 * 2;
  float4 e0 = e4[0], e1 = e4[1];
  float4 d0 = d4[0], d1 = d4[1];

  float se = e0.x*e0.x + e0.y*e0.y + e0.z*e0.z + e0.w*e0.w
           + e1.x*e1.x + e1.y*e1.y + e1.z*e1.z + e1.w*e1.w;
  float sd = d0.x*d0.x + d0.y*d0.y + d0.z*d0.z + d0.w*d0.w
           + d1.x*d1.x + d1.y*d1.y + d1.z*d1.z + d1.w*d1.w;
  float sp = e0.x*d0.x + e0.y*d0.y + e0.z*d0.z + e0.w*d0.w
           + e1.x*d1.x + e1.y*d1.y + e1.z*d1.z + e1.w*d1.w;
#pragma unroll
  for (int off = 1; off < 16; off <<= 1) {
    se += __shfl_xor(se, off);
    sd += __shfl_xor(sd, off);
    sp += __shfl_xor(sp, off);
  }
  float ie = rsqrtf(se), id = rsqrtf(sd);

  uint2 ua, ub;
  ua.x = pk4_fp8(e0.x * ie, e0.y * ie, e0.z * ie, e0.w * ie);
  ua.y = pk4_fp8(e1.x * ie, e1.y * ie, e1.z * ie, e1.w * ie);
  ub.x = pk4_fp8(d0.x * id, d0.y * id, d0.z * id, d0.w * id);
  ub.y = pk4_fp8(d1.x * id, d1.y * id, d1.z * id, d1.w * id);
  A8[(size_t)row * 16 + l16] = ua;   // row stride 128 B (128 fp8)
  B8[(size_t)row * 16 + l16] = ub;

  if (l16 == 0) {
    float en = se * ie, dn = sd * id;                 // sqrt via x*rsqrt(x)
    float s  = sp / (en * dn + 1e-5f);
    logit_p[row] = -fmaxf(1.25f - s, 0.0f) * (s - 0.75f) * 64.0f;
  }
}

// ---------------- kernel 2: banded fp8 GEMM (double-buffered LDS) + last-block tail ----------------
// grid = (64 bands) x (8 splits); each block sweeps 8 tiles with one barrier per
// tile: next tile's global_load_lds is issued BEFORE compute and lands across
// the full tile window. fp8 halves LDS bytes vs bf16 (tile A+B = 32 KB).
__global__ __launch_bounds__(256, 2) void k_main(const unsigned char* __restrict__ A,
                                                 const unsigned char* __restrict__ B,
                                                 float* __restrict__ bandsum,
                                                 const float* __restrict__ logit_p,
                                                 unsigned* __restrict__ counter,
                                                 float* __restrict__ out) {
  __shared__ __align__(16) unsigned char As[2 * 16384];   // 2 bufs x 128 rows x 128 B
  __shared__ __align__(16) unsigned char Bs[2 * 16384];
  __shared__ float part[4][256];
  __shared__ unsigned lastFlag;

  const int t  = threadIdx.x;
  const int T  = blockIdx.x;   // band: tiles with (bx-by)&63 == T
  const int sp = blockIdx.y;   // split along the band

#pragma unroll
  for (int q = 0; q < 4; ++q) part[q][t] = 0.0f;

  const int lane = t & 63;
  const int w = t >> 6, wrow = w >> 1, wcol = w & 1;
  const int l15 = lane & 15, quad = lane >> 4;
  const int x7 = l15 & 7;
  const int qh = quad >> 1, ql8 = (quad & 1) * 8;

  // staging: row-within-32 = t>>3, 16B-chunk slot = t&7, xor swizzle
  const int rl = t >> 3;
  const int lgoff = rl * 128 + ((t & 7) ^ (rl & 7)) * 16;  // global byte offset in 32-row group
  const int lloff = t * 16;                                 // LDS byte offset (contiguous)

  const char* Ab = (const char*)A;
  const char* Bb = (const char*)B;

  float dreg[28];
#pragma unroll
  for (int i = 0; i < 28; ++i) dreg[i] = 0.0f;

  // frag read bases (byte offsets within a 16 KB buffer)
  const int arow = (wrow * 64 + l15) * 128;
  const int brow = (wcol * 64 + l15) * 128;

  // ---- stage tile 0 into buf 0 ----
  {
    const int by = sp * 8;
    const int bx = (by + T) & 63;
    const char* Ag = Ab + (size_t)by * 16384 + lgoff;
    const char* Bg = Bb + (size_t)bx * 16384 + lgoff;
#pragma unroll
    for (int j = 0; j < 4; ++j) {
      gl_lds16(Ag + j * 4096, (char*)As + j * 4096 + lloff);
      gl_lds16(Bg + j * 4096, (char*)Bs + j * 4096 + lloff);
    }
  }
  __syncthreads();   // vmcnt(0): tile 0 staged

  for (int it = 0; it < 8; ++it) {
    const int p = it & 1;

    if (it < 7) {    // issue next tile's stage into the other buffer; lands by tile-end barrier
      const int by = sp * 8 + it + 1;
      const int bx = (by + T) & 63;
      const char* Ag = Ab + (size_t)by * 16384 + lgoff;
      const char* Bg = Bb + (size_t)bx * 16384 + lgoff;
      char* Ad = (char*)As + (p ^ 1) * 16384 + lloff;
      char* Bd = (char*)Bs + (p ^ 1) * 16384 + lloff;
#pragma unroll
      for (int j = 0; j < 4; ++j) {
        gl_lds16(Ag + j * 4096, Ad + j * 4096);
        gl_lds16(Bg + j * 4096, Bd + j * 4096);
      }
    }

    f32x4 acc[4][4];
    const f32x4 zv = {0.f, 0.f, 0.f, 0.f};
#pragma unroll
    for (int r = 0; r < 4; ++r)
#pragma unroll
      for (int c = 0; c < 4; ++c) acc[r][c] = zv;

    const char* Abuf = (const char*)As + p * 16384;
    const char* Bbuf = (const char*)Bs + p * 16384;

#pragma unroll
    for (int ks = 0; ks < 4; ++ks) {
      long a[4], b[4];
      const int off = (((ks * 2 + qh) ^ x7) * 16) + ql8;   // swizzled 8B k-chunk
#pragma unroll
      for (int r = 0; r < 4; ++r)
        a[r] = *reinterpret_cast<const long*>(Abuf + arow + r * 2048 + off);
#pragma unroll
      for (int c = 0; c < 4; ++c)
        b[c] = *reinterpret_cast<const long*>(Bbuf + brow + c * 2048 + off);
#pragma unroll
      for (int r = 0; r < 4; ++r)
#pragma unroll
        for (int c = 0; c < 4; ++c)
          acc[r][c] = __builtin_amdgcn_mfma_f32_16x16x32_fp8_fp8(a[r], b[c], acc[r][c], 0, 0, 0);
    }

    // ---- epilogue: pure register math, native v_exp ----
    // 64*log2(e) = 92.33248262 ; 0.25*64*log2(e) = 23.08312065
#pragma unroll
    for (int dlt = -3; dlt <= 3; ++dlt) {
#pragma unroll
      for (int g = 0; g < 4; ++g) {
        float s = 0.0f;
#pragma unroll
        for (int r = 0; r < 4; ++r) {
          int c = r + dlt;
          if (c < 0 || c > 3) continue;
          float sn = acc[r][c][g];
          float an = fmaxf(sn + 0.25f, 0.0f);
          float u  = fmaf(sn, 92.332483f, -23.083121f);
          s += EXP2(an * u);
        }
        dreg[(dlt + 3) * 4 + g] += s;
      }
    }

    __syncthreads();   // one barrier/tile: drains ds_reads of buf p AND stage into buf p^1
  }

  // ---- single flush: shfl tree over 4-lane collision groups -> LDS -> global ----
  const int  Qoff = (wcol - wrow) * 64 + 127;
  const int  v    = l15 - quad * 4;
  const bool leader = (quad == 0) || (l15 <= 3);
  const bool ok1 = (l15 <= 11) && (quad <= 2);
  const bool ok2 = (l15 <= 7)  && (quad <= 1);

#pragma unroll
  for (int dlt = -3; dlt <= 3; ++dlt) {
#pragma unroll
    for (int g = 0; g < 4; ++g) {
      float s = dreg[(dlt + 3) * 4 + g];
      float t1 = __shfl_down(s, 20); s += ok1 ? t1 : 0.0f;  // partner quad+1
      float t2 = __shfl_down(s, 40); s += ok2 ? t2 : 0.0f;  // partners quad+2, quad+3
      int ld = Qoff + dlt * 16 - g + v;
      if (leader) unsafeAtomicAdd(&part[w][ld], s);         // distinct ld per leader
    }
  }
  __syncthreads();

  // band-0 slot 127 corresponds to d=0 only, which the tail skips
  if (t < 255) {
    float vv = part[0][t] + part[1][t] + part[2][t] + part[3][t];
    unsafeAtomicAdd(&bandsum[T * 256 + t], vv);
  }

  // ---- last-block-done detection (device-scope atomics + barrier vmcnt order
  //      the counter bump after the bandsum adds; no release fence needed) ----
  __syncthreads();
  if (t == 0) lastFlag = (atomicAdd(counter, 1u) == 511u) ? 1u : 0u;
  __syncthreads();
  if (!lastFlag) return;

  // ================= scalar tail (one block, 256 threads, batched loads) =================
  __threadfence();          // acquire: invalidate stale lines so bandsum loads are fresh
  float* sm = part[0];

  float lp[32];
#pragma unroll
  for (int k = 0; k < 32; ++k) lp[k] = logit_p[t + 256 * k];

  float m = lp[0];
#pragma unroll
  for (int k = 1; k < 32; ++k) m = fmaxf(m, lp[k]);
#pragma unroll
  for (int off = 32; off; off >>= 1) m = fmaxf(m, __shfl_down(m, off));
  if (lane == 0) sm[w] = m;
  __syncthreads();
  m = fmaxf(fmaxf(sm[0], sm[1]), fmaxf(sm[2], sm[3]));
  __syncthreads();

  float s = 0.0f;
#pragma unroll
  for (int k = 0; k < 32; ++k) s += __expf(lp[k] - m);
#pragma unroll
  for (int off = 32; off; off >>= 1) s += __shfl_down(s, off);
  if (lane == 0) sm[w] = s;
  __syncthreads();
  s = sm[0] + sm[1] + sm[2] + sm[3];
  float lse_p = m + __logf(s);
  __syncthreads();

  // thread t handles d = t + 256k: d>>7 = (t>>7) + 2k, d&127 = t&127
  const int o  = t & 127;
  const int hi = t >> 7;
  float bs1[32], bs2[32];
#pragma unroll
  for (int k = 0; k < 32; ++k) {
    int Ta = hi + 2 * k;
    bs1[k] = bandsum[Ta * 256 + o + 127];
    bs2[k] = o ? bandsum[((Ta + 1) & 63) * 256 + o - 1] : 0.0f;
  }
  float acc = 0.0f;
#pragma unroll
  for (int k = 0; k < 32; ++k) {
    if (t == 0 && k == 0) continue;   // d=0 excluded
    float se = bs1[k] + bs2[k];
    float x = __logf(se) + lse_p;
    acc += fmaxf(x, 0.0f) + __logf(1.0f + __expf(-fabsf(x)));
  }
#pragma unroll
  for (int off = 32; off; off >>= 1) acc += __shfl_down(acc, off);
  if (lane == 0) sm[w] = acc;
  __syncthreads();
  if (t == 0) out[0] = (sm[0] + sm[1] + sm[2] + sm[3]) * (1.0f / 8191.0f);
}

// ---------------- launcher ----------------
extern "C" void kernel_launch(void* const* d_in, const int* in_sizes, int n_in,
                              void* d_out, int out_size, void* d_ws, size_t ws_size,
                              hipStream_t stream) {
  const float* enc = (const float*)d_in[0];
  const float* dec = (const float*)d_in[1];
  float* ws = (float*)d_ws;

  float*    logit_p = ws;                               // 8192
  float*    bandsum = ws + 8192;                        // 64*256 = 16384
  unsigned* counter = (unsigned*)(ws + 8192 + 16384);   // 1 (+pad)
  uint2*    A8      = (uint2*)(ws + 8192 + 16384 + 256);     // 8192x128 fp8 = 1 MB
  uint2*    B8      = (uint2*)((char*)A8 + 1048576);
  float*    out     = (float*)d_out;

  k_prep<<<NN / 16, 256, 0, stream>>>(enc, dec, A8, B8, logit_p, bandsum, counter);
  dim3 grid(64, 8);
  k_main<<<grid, 256, 0, stream>>>((const unsigned char*)A8, (const unsigned char*)B8,
                                   bandsum, logit_p, counter, out);
}